// Round 1
// baseline (269.053 us; speedup 1.0000x reference)
//
#include <hip/hip_runtime.h>
#include <hip/hip_bf16.h>
#include <math.h>

// Problem constants (MultiheadAttention: B=2, N=2048, E=1024, H=16, hd=64)
#define EDIM 1024
#define N3E  3072
#define NSEQ 2048
#define NB   2
#define NH   16
#define HD   64
#define MTOT (NB*NSEQ)   // 4096

// Workspace layout (bytes):
//   Xb  bf16 [4096][1024]                  :      0 .. 8388608
//   Wt  bf16 [3072][1024] (perm+transposed): 8388608 .. 14680064
//   Bp  f32  [3072] (permuted bias)        : 14680064 .. +16384
//   QKV bf16 [3][2][16][2048][64]          : 14696448 .. +25165824  (~38 MB total)

typedef __attribute__((ext_vector_type(8))) short bf16x8;
typedef __attribute__((ext_vector_type(4))) float f32x4;

__device__ __forceinline__ short f2bf(float f) {
    union { float f; unsigned u; } v; v.f = f;
    unsigned r = v.u + 0x7FFFu + ((v.u >> 16) & 1u);   // RNE
    return (short)(r >> 16);
}

// ---------- prep 1: x fp32 -> bf16 ----------
__global__ __launch_bounds__(256) void k_convert_x(const float* __restrict__ x,
                                                   short* __restrict__ xb, int n4) {
    int i = blockIdx.x * blockDim.x + threadIdx.x;
    int stride = gridDim.x * blockDim.x;
    for (; i < n4; i += stride) {
        float4 v = ((const float4*)x)[i];
        ushort4 o;
        o.x = (unsigned short)f2bf(v.x);
        o.y = (unsigned short)f2bf(v.y);
        o.z = (unsigned short)f2bf(v.z);
        o.w = (unsigned short)f2bf(v.w);
        ((ushort4*)xb)[i] = o;
    }
}

// ---------- prep 2: W[k][c] fp32 -> Wt[c'][k] bf16 ----------
// actual col c = (e*16+h)*3 + qkv ; logical c' = qkv*1024 + h*64 + e
// grid (1024/64, 3072/96), 256 threads; LDS-tiled so both sides are coalesced.
__global__ __launch_bounds__(256) void k_transpose_w(const float* __restrict__ w,
                                                     short* __restrict__ wt) {
    __shared__ float T[96][68];   // [c][k], padded
    int k0 = blockIdx.x * 64;
    int c0 = blockIdx.y * 96;
    int t = threadIdx.x;
    {
        int kr = t >> 2;            // 0..63
        int cb = (t & 3) * 24;      // 0,24,48,72
        const float* src = w + (size_t)(k0 + kr) * N3E + c0 + cb;
        #pragma unroll
        for (int i = 0; i < 24; i += 4) {
            float4 v = *(const float4*)(src + i);
            T[cb + i + 0][kr] = v.x;
            T[cb + i + 1][kr] = v.y;
            T[cb + i + 2][kr] = v.z;
            T[cb + i + 3][kr] = v.w;
        }
    }
    __syncthreads();
    int kk = (t & 7) * 8;
    #pragma unroll
    for (int p = 0; p < 3; ++p) {
        int cc = p * 32 + (t >> 3);
        int ca = c0 + cc;
        int e = ca / 48, h = (ca % 48) / 3, q = ca % 3;
        int cp = q * 1024 + h * 64 + e;
        bf16x8 o;
        #pragma unroll
        for (int j = 0; j < 8; ++j) o[j] = f2bf(T[cc][kk + j]);
        *(bf16x8*)(wt + (size_t)cp * EDIM + k0 + kk) = o;
    }
}

// ---------- prep 3: bias permute ----------
__global__ void k_perm_bias(const float* __restrict__ b, float* __restrict__ bp) {
    int c = blockIdx.x * 256 + threadIdx.x;
    if (c >= N3E) return;
    int e = c / 48, h = (c % 48) / 3, q = c % 3;
    bp[q * 1024 + h * 64 + e] = b[c];
}

// ---------- QKV GEMM: Y[m][c'] = sum_k Xb[m][k]*Wt[c'][k] + Bp[c'] ----------
// 128x128 tile, BK=32, 4 waves (2x2), 4x4 16x16x32 MFMA per wave.
// Epilogue scatters directly into QKV[qkv][b][h][n][e] (contiguous-e stores).
#define BMT 128
#define BNT 128
#define BKT 32
#define LDT 56   // padded leading dim (112B rows: 16B-aligned, 7-coprime bank spread)
__global__ __launch_bounds__(256) void k_qkv_gemm(const short* __restrict__ xb,
        const short* __restrict__ wt, const float* __restrict__ bp,
        short* __restrict__ qkv) {
    __shared__ short Al[BMT][LDT];
    __shared__ short Bl[BNT][LDT];
    int t = threadIdx.x;
    int lane = t & 63, wv = t >> 6;
    int g = lane >> 4, r = lane & 15;
    int wr = wv >> 1, wc = wv & 1;
    int m0 = blockIdx.x * BMT, n0 = blockIdx.y * BNT;
    int srow = t >> 1, skc = (t & 1) * 16;   // staging: row = t/2, 16 elems per half-row
    const short* xs = xb + (size_t)(m0 + srow) * EDIM + skc;
    const short* wsrc = wt + (size_t)(n0 + srow) * EDIM + skc;
    f32x4 acc[4][4] = {};
    for (int k0 = 0; k0 < EDIM; k0 += BKT) {
        bf16x8 a0 = *(const bf16x8*)(xs + k0);
        bf16x8 a1 = *(const bf16x8*)(xs + k0 + 8);
        bf16x8 b0 = *(const bf16x8*)(wsrc + k0);
        bf16x8 b1 = *(const bf16x8*)(wsrc + k0 + 8);
        *(bf16x8*)(&Al[srow][skc])     = a0;
        *(bf16x8*)(&Al[srow][skc + 8]) = a1;
        *(bf16x8*)(&Bl[srow][skc])     = b0;
        *(bf16x8*)(&Bl[srow][skc + 8]) = b1;
        __syncthreads();
        bf16x8 af[4], bfr[4];
        #pragma unroll
        for (int mt = 0; mt < 4; ++mt)
            af[mt] = *(const bf16x8*)(&Al[wr*64 + mt*16 + r][g*8]);
        #pragma unroll
        for (int nt = 0; nt < 4; ++nt)
            bfr[nt] = *(const bf16x8*)(&Bl[wc*64 + nt*16 + r][g*8]);
        #pragma unroll
        for (int mt = 0; mt < 4; ++mt)
            #pragma unroll
            for (int nt = 0; nt < 4; ++nt)
                acc[mt][nt] = __builtin_amdgcn_mfma_f32_16x16x32_bf16(
                                  af[mt], bfr[nt], acc[mt][nt], 0, 0, 0);
        __syncthreads();
    }
    // epilogue: bias + scatter to QKV[qkv][b][h][n][e]
    #pragma unroll
    for (int nt = 0; nt < 4; ++nt) {
        int cp = n0 + wc*64 + nt*16 + r;       // logical column c'
        float bias = bp[cp];
        int q = cp >> 10, h = (cp >> 6) & 15, e = cp & 63;
        #pragma unroll
        for (int mt = 0; mt < 4; ++mt) {
            #pragma unroll
            for (int rg = 0; rg < 4; ++rg) {
                int m = m0 + wr*64 + mt*16 + g*4 + rg;   // C row = (lane>>4)*4+reg
                int bb = m >> 11, n = m & 2047;
                qkv[((((size_t)q*NB + bb)*NH + h)*NSEQ + n)*HD + e] =
                    f2bf(acc[mt][nt][rg] + bias);
            }
        }
    }
}

// ---------- flash attention ----------
// grid (32 qblocks, 16 heads, 2 batch), 4 waves; wave owns 16 q-rows.
// KV tiles of 64; K row-major LDS (padded), V transposed LDS, P per-wave LDS.
__global__ __launch_bounds__(256) void k_attn(const short* __restrict__ qkv,
                                              float* __restrict__ out) {
    __shared__ short Kl[64][72];       // [kv][d] padded (+8: 2-way max on frag reads)
    __shared__ short Vt[64][72];       // [d][kv] padded
    __shared__ short Pl[4][16][72];    // per-wave P [qrow][kv]
    int t = threadIdx.x, lane = t & 63, wv = t >> 6;
    int g = lane >> 4, r = lane & 15;
    int qb = blockIdx.x, h = blockIdx.y, b = blockIdx.z;
    const size_t HS = (size_t)NSEQ * HD;
    const short* Qp = qkv + ((size_t)(0*NB + b)*NH + h) * HS;
    const short* Kp = qkv + ((size_t)(1*NB + b)*NH + h) * HS;
    const short* Vp = qkv + ((size_t)(2*NB + b)*NH + h) * HS;
    int q0 = qb * 64 + wv * 16;
    // Q hoisted to registers: lane holds Q[q0+r][ks*32 + g*8 .. +8]
    bf16x8 qf0 = *(const bf16x8*)(Qp + (size_t)(q0 + r)*HD + g*8);
    bf16x8 qf1 = *(const bf16x8*)(Qp + (size_t)(q0 + r)*HD + 32 + g*8);
    f32x4 o[4] = {};
    float mrun[4] = {-INFINITY, -INFINITY, -INFINITY, -INFINITY};
    float lrun[4] = {0.f, 0.f, 0.f, 0.f};
    int skv = t >> 2, sd = (t & 3) * 16;        // K staging map
    int vkv = (t >> 3) * 2, vd = (t & 7) * 8;   // V staging map (2 kv packed / b32)
    for (int kt = 0; kt < NSEQ; kt += 64) {
        {   // stage K tile
            const short* src = Kp + (size_t)(kt + skv)*HD + sd;
            bf16x8 k0v = *(const bf16x8*)src;
            bf16x8 k1v = *(const bf16x8*)(src + 8);
            *(bf16x8*)(&Kl[skv][sd])     = k0v;
            *(bf16x8*)(&Kl[skv][sd + 8]) = k1v;
        }
        {   // stage V tile transposed (pack kv pairs into b32 writes)
            const short* src = Vp + (size_t)(kt + vkv)*HD + vd;
            bf16x8 va = *(const bf16x8*)src;
            bf16x8 vb = *(const bf16x8*)(src + HD);
            #pragma unroll
            for (int i = 0; i < 8; ++i) {
                unsigned pk = (unsigned short)va[i]
                            | ((unsigned)(unsigned short)vb[i] << 16);
                *(unsigned*)(&Vt[vd + i][vkv]) = pk;
            }
        }
        __syncthreads();
        // S = 0.25 * Q K^T   (B-frag = K rows, contiguous d)
        f32x4 s[4];
        #pragma unroll
        for (int jt = 0; jt < 4; ++jt) {
            bf16x8 kf0 = *(const bf16x8*)(&Kl[jt*16 + r][g*8]);
            bf16x8 kf1 = *(const bf16x8*)(&Kl[jt*16 + r][32 + g*8]);
            f32x4 sv = {};
            sv = __builtin_amdgcn_mfma_f32_16x16x32_bf16(qf0, kf0, sv, 0, 0, 0);
            sv = __builtin_amdgcn_mfma_f32_16x16x32_bf16(qf1, kf1, sv, 0, 0, 0);
            s[jt] = sv * 0.25f;   // scale = 1/sqrt(num_heads) per reference!
        }
        // online softmax: rows live in 16-lane groups (cols = l&15), reg rg = row
        float al[4];
        #pragma unroll
        for (int rg = 0; rg < 4; ++rg) {
            float v = fmaxf(fmaxf(s[0][rg], s[1][rg]), fmaxf(s[2][rg], s[3][rg]));
            v = fmaxf(v, __shfl_xor(v, 1));
            v = fmaxf(v, __shfl_xor(v, 2));
            v = fmaxf(v, __shfl_xor(v, 4));
            v = fmaxf(v, __shfl_xor(v, 8));
            float mnew = fmaxf(mrun[rg], v);
            float a = __expf(mrun[rg] - mnew);
            mrun[rg] = mnew;
            al[rg] = a;
            float ps = 0.f;
            #pragma unroll
            for (int jt = 0; jt < 4; ++jt) {
                float p = __expf(s[jt][rg] - mnew);
                s[jt][rg] = p;
                ps += p;
            }
            ps += __shfl_xor(ps, 1);
            ps += __shfl_xor(ps, 2);
            ps += __shfl_xor(ps, 4);
            ps += __shfl_xor(ps, 8);
            lrun[rg] = lrun[rg] * a + ps;
        }
        #pragma unroll
        for (int dt = 0; dt < 4; ++dt) {
            f32x4 ov = o[dt];
            ov[0] *= al[0]; ov[1] *= al[1]; ov[2] *= al[2]; ov[3] *= al[3];
            o[dt] = ov;
        }
        // P -> per-wave LDS (bf16); C row = g*4+rg, col = jt*16+r
        #pragma unroll
        for (int jt = 0; jt < 4; ++jt)
            #pragma unroll
            for (int rg = 0; rg < 4; ++rg)
                Pl[wv][g*4 + rg][jt*16 + r] = f2bf(s[jt][rg]);
        // O += P V   (A-frag from Pl, B-frag from Vt)
        bf16x8 p0 = *(const bf16x8*)(&Pl[wv][r][g*8]);
        bf16x8 p1 = *(const bf16x8*)(&Pl[wv][r][32 + g*8]);
        #pragma unroll
        for (int dt = 0; dt < 4; ++dt) {
            bf16x8 vf0 = *(const bf16x8*)(&Vt[dt*16 + r][g*8]);
            bf16x8 vf1 = *(const bf16x8*)(&Vt[dt*16 + r][32 + g*8]);
            o[dt] = __builtin_amdgcn_mfma_f32_16x16x32_bf16(p0, vf0, o[dt], 0, 0, 0);
            o[dt] = __builtin_amdgcn_mfma_f32_16x16x32_bf16(p1, vf1, o[dt], 0, 0, 0);
        }
        __syncthreads();
    }
    // epilogue: out[b][n][h*64 + d]  (fp32, 16 contiguous lanes = 64B stores)
    #pragma unroll
    for (int rg = 0; rg < 4; ++rg) {
        float inv = 1.0f / lrun[rg];
        int n = q0 + g*4 + rg;
        float* dst = out + ((size_t)(b*NSEQ + n))*EDIM + h*HD;
        #pragma unroll
        for (int dt = 0; dt < 4; ++dt)
            dst[dt*16 + r] = o[dt][rg] * inv;
    }
}

extern "C" void kernel_launch(void* const* d_in, const int* in_sizes, int n_in,
                              void* d_out, int out_size, void* d_ws, size_t ws_size,
                              hipStream_t stream) {
    const float* x  = (const float*)d_in[0];
    const float* w  = (const float*)d_in[1];
    const float* bq = (const float*)d_in[2];
    float* outp = (float*)d_out;
    char* ws = (char*)d_ws;
    short* Xb  = (short*)(ws);
    short* Wt  = (short*)(ws + 8388608);
    float* Bp  = (float*)(ws + 8388608 + 6291456);
    short* QKV = (short*)(ws + 8388608 + 6291456 + 16384);
    k_convert_x<<<dim3(2048), dim3(256), 0, stream>>>(x, Xb, (MTOT*EDIM)/4);
    k_transpose_w<<<dim3(16, 32), dim3(256), 0, stream>>>(w, Wt);
    k_perm_bias<<<dim3(12), dim3(256), 0, stream>>>(bq, Bp);
    k_qkv_gemm<<<dim3(32, 24), dim3(256), 0, stream>>>(Xb, Wt, Bp, QKV);
    k_attn<<<dim3(32, 16, 2), dim3(256), 0, stream>>>(QKV, outp);
}

// Round 3
// 220.442 us; speedup vs baseline: 1.2205x; 1.2205x over previous
//
#include <hip/hip_runtime.h>
#include <hip/hip_bf16.h>
#include <math.h>

// Problem constants (MultiheadAttention: B=2, N=2048, E=1024, H=16, hd=64)
#define EDIM 1024
#define N3E  3072
#define NSEQ 2048
#define NB   2
#define NH   16
#define HD   64
#define MTOT (NB*NSEQ)   // 4096

typedef __attribute__((ext_vector_type(8))) short bf16x8;
typedef __attribute__((ext_vector_type(4))) float f32x4;

#define SCALE2 0.360673760222241f   // 0.25 * log2(e)

__device__ __forceinline__ short f2bf(float f) {
    union { float f; unsigned u; } v; v.f = f;
    unsigned r = v.u + 0x7FFFu + ((v.u >> 16) & 1u);   // RNE
    return (short)(r >> 16);
}

__device__ __forceinline__ unsigned cvtpk(float lo, float hi) {
    unsigned r;
    asm("v_cvt_pk_bf16_f32 %0, %1, %2" : "=v"(r) : "v"(lo), "v"(hi));
    return r;
}

__device__ __forceinline__ void gload16(const void* g, void* l) {
    __builtin_amdgcn_global_load_lds(
        (const __attribute__((address_space(1))) unsigned int*)g,
        (__attribute__((address_space(3))) unsigned int*)l, 16, 0, 0);
}

// ---------- prep 1: x fp32 -> bf16 ----------
__global__ __launch_bounds__(256) void k_convert_x(const float* __restrict__ x,
                                                   short* __restrict__ xb, int n4) {
    int i = blockIdx.x * blockDim.x + threadIdx.x;
    int stride = gridDim.x * blockDim.x;
    for (; i < n4; i += stride) {
        float4 v = ((const float4*)x)[i];
        ushort4 o;
        o.x = (unsigned short)f2bf(v.x);
        o.y = (unsigned short)f2bf(v.y);
        o.z = (unsigned short)f2bf(v.z);
        o.w = (unsigned short)f2bf(v.w);
        ((ushort4*)xb)[i] = o;
    }
}

// ---------- prep 2: W[k][c] fp32 -> Wt[c'][k] bf16 ----------
// actual col c = (e*16+h)*3 + qkv ; logical c' = qkv*1024 + h*64 + e
__global__ __launch_bounds__(256) void k_transpose_w(const float* __restrict__ w,
                                                     short* __restrict__ wt) {
    __shared__ float T[96][68];
    int k0 = blockIdx.x * 64;
    int c0 = blockIdx.y * 96;
    int t = threadIdx.x;
    {
        int kr = t >> 2;
        int cb = (t & 3) * 24;
        const float* src = w + (size_t)(k0 + kr) * N3E + c0 + cb;
        #pragma unroll
        for (int i = 0; i < 24; i += 4) {
            float4 v = *(const float4*)(src + i);
            T[cb + i + 0][kr] = v.x;
            T[cb + i + 1][kr] = v.y;
            T[cb + i + 2][kr] = v.z;
            T[cb + i + 3][kr] = v.w;
        }
    }
    __syncthreads();
    int kk = (t & 7) * 8;
    #pragma unroll
    for (int p = 0; p < 3; ++p) {
        int cc = p * 32 + (t >> 3);
        int ca = c0 + cc;
        int e = ca / 48, h = (ca % 48) / 3, q = ca % 3;
        int cp = q * 1024 + h * 64 + e;
        bf16x8 o;
        #pragma unroll
        for (int j = 0; j < 8; ++j) o[j] = f2bf(T[cc][kk + j]);
        *(bf16x8*)(wt + (size_t)cp * EDIM + k0 + kk) = o;
    }
}

// ---------- prep 3: bias permute ----------
__global__ void k_perm_bias(const float* __restrict__ b, float* __restrict__ bp) {
    int c = blockIdx.x * 256 + threadIdx.x;
    if (c >= N3E) return;
    int e = c / 48, h = (c % 48) / 3, q = c % 3;
    bp[q * 1024 + h * 64 + e] = b[c];
}

// ---------- QKV GEMM, m97 structure: linear LDS + global_load_lds(16B) ----------
__global__ __launch_bounds__(256) void k_qkv_gemm(const short* __restrict__ xb,
        const short* __restrict__ wt, const float* __restrict__ bp,
        short* __restrict__ qkv) {
    __shared__ short Al[128][32];
    __shared__ short Bl[128][32];
    int t = threadIdx.x, lane = t & 63, wv = t >> 6;
    int g = lane >> 4, r = lane & 15;
    int wr = wv >> 1, wc = wv & 1;
    int m0 = blockIdx.x * 128, n0 = blockIdx.y * 128;
    // staging: lds chunk (wv*2+j) of 1KB; row = wv*32 + j*16 + lane/4, col = (lane&3)*8 shorts
    int srow = wv * 32 + (lane >> 2);
    int scol = (lane & 3) * 8;
    const short* ga0 = xb + (size_t)(m0 + srow) * EDIM + scol;
    const short* ga1 = ga0 + (size_t)16 * EDIM;
    const short* gb0 = wt + (size_t)(n0 + srow) * EDIM + scol;
    const short* gb1 = gb0 + (size_t)16 * EDIM;
    char* la0 = (char*)(&Al[0][0]) + wv * 2048;
    char* lb0 = (char*)(&Bl[0][0]) + wv * 2048;
    f32x4 acc[4][4] = {};
    for (int k0 = 0; k0 < EDIM; k0 += 32) {
        gload16(ga0 + k0, la0);
        gload16(ga1 + k0, la0 + 1024);
        gload16(gb0 + k0, lb0);
        gload16(gb1 + k0, lb0 + 1024);
        __syncthreads();
        bf16x8 af[4], bfr[4];
        #pragma unroll
        for (int mt = 0; mt < 4; ++mt)
            af[mt] = *(const bf16x8*)(&Al[wr*64 + mt*16 + r][g*8]);
        #pragma unroll
        for (int nt = 0; nt < 4; ++nt)
            bfr[nt] = *(const bf16x8*)(&Bl[wc*64 + nt*16 + r][g*8]);
        #pragma unroll
        for (int mt = 0; mt < 4; ++mt)
            #pragma unroll
            for (int nt = 0; nt < 4; ++nt)
                acc[mt][nt] = __builtin_amdgcn_mfma_f32_16x16x32_bf16(
                                  af[mt], bfr[nt], acc[mt][nt], 0, 0, 0);
        __syncthreads();
    }
    #pragma unroll
    for (int nt = 0; nt < 4; ++nt) {
        int cp = n0 + wc*64 + nt*16 + r;
        float bias = bp[cp];
        int q = cp >> 10, h = (cp >> 6) & 15, e = cp & 63;
        #pragma unroll
        for (int mt = 0; mt < 4; ++mt) {
            #pragma unroll
            for (int rg = 0; rg < 4; ++rg) {
                int m = m0 + wr*64 + mt*16 + g*4 + rg;
                int bb = m >> 11, n = m & 2047;
                qkv[((((size_t)q*NB + bb)*NH + h)*NSEQ + n)*HD + e] =
                    f2bf(acc[mt][nt][rg] + bias);
            }
        }
    }
}

// ---------- flash attention, swapped-operand / lane-local softmax ----------
// grid (16 qblocks, 16 heads, 2 batch), 4 waves x 32 q-rows, KV tiles of 64.
// S^T = mfma(K,Q): lane (g,r) holds S[q=r][kv=16jt+4g+rg] -> softmax lane-local.
// O^T = mfma(V^T, P): rescale lane-local; P bounced through XOR-swizzled LDS.
__global__ __launch_bounds__(256) void k_attn(const short* __restrict__ qkv,
                                              float* __restrict__ out) {
    __shared__ short Kl[64][72];
    __shared__ short Vt[64][72];         // [d][kv]
    __shared__ short Pl[4][2][16][64];   // per-wave, per-half, XOR-swizzled rows
    int t = threadIdx.x, lane = t & 63, wv = t >> 6;
    int g = lane >> 4, r = lane & 15;
    int qb = blockIdx.x, h = blockIdx.y, b = blockIdx.z;
    const size_t HS = (size_t)NSEQ * HD;
    const short* Qp = qkv + ((size_t)(0*NB + b)*NH + h) * HS;
    const short* Kp = qkv + ((size_t)(1*NB + b)*NH + h) * HS;
    const short* Vp = qkv + ((size_t)(2*NB + b)*NH + h) * HS;
    int q0 = qb * 128 + wv * 32;
    // Q frags: qf[u][c] = Q[q0+u*16+r][c*32+g*8 ..+7]
    bf16x8 qf00 = *(const bf16x8*)(Qp + (size_t)(q0 + r)*HD + g*8);
    bf16x8 qf01 = *(const bf16x8*)(Qp + (size_t)(q0 + r)*HD + 32 + g*8);
    bf16x8 qf10 = *(const bf16x8*)(Qp + (size_t)(q0 + 16 + r)*HD + g*8);
    bf16x8 qf11 = *(const bf16x8*)(Qp + (size_t)(q0 + 16 + r)*HD + 32 + g*8);
    f32x4 o0[4] = {}, o1[4] = {};
    float m0r = -3.0e38f, m1r = -3.0e38f, l0r = 0.f, l1r = 0.f;
    // staging maps
    int skv = t >> 2, sd = (t & 3) * 16;          // K: 1 kv row, 16 d per lane
    int vkv = (t >> 4) * 4, vd = (t & 15) * 4;    // V: 4 kv x 4 d block per lane
    int rx = (r & 7) << 4;                        // P swizzle
    char* prow0 = (char*)(&Pl[wv][0][0][0]) + r * 128;
    char* prow1 = prow0 + 2048;
    bf16x8 kk0, kk1; ushort4 vv0, vv1, vv2, vv3;
    const short* Kst = Kp + (size_t)skv * HD + sd;
    const short* Vst = Vp + (size_t)vkv * HD + vd;
    // prologue: load + write tile 0
    kk0 = *(const bf16x8*)(Kst);
    kk1 = *(const bf16x8*)(Kst + 8);
    vv0 = *(const ushort4*)(Vst);
    vv1 = *(const ushort4*)(Vst + HD);
    vv2 = *(const ushort4*)(Vst + 2*HD);
    vv3 = *(const ushort4*)(Vst + 3*HD);
    {
        *(bf16x8*)(&Kl[skv][sd]) = kk0;
        *(bf16x8*)(&Kl[skv][sd + 8]) = kk1;
        #pragma unroll
        for (int i = 0; i < 4; ++i) {
            unsigned lo = (unsigned)((const unsigned short*)&vv0)[i]
                        | ((unsigned)((const unsigned short*)&vv1)[i] << 16);
            unsigned hi = (unsigned)((const unsigned short*)&vv2)[i]
                        | ((unsigned)((const unsigned short*)&vv3)[i] << 16);
            uint2 wrd; wrd.x = lo; wrd.y = hi;
            *(uint2*)(&Vt[vd + i][vkv]) = wrd;
        }
    }
    for (int kt = 0; kt < NSEQ; kt += 64) {
        __syncthreads();
        bool more = (kt + 64) < NSEQ;
        if (more) {   // T14: issue next tile's global loads before compute
            kk0 = *(const bf16x8*)(Kst + (size_t)(kt + 64) * HD);
            kk1 = *(const bf16x8*)(Kst + (size_t)(kt + 64) * HD + 8);
            vv0 = *(const ushort4*)(Vst + (size_t)(kt + 64) * HD);
            vv1 = *(const ushort4*)(Vst + (size_t)(kt + 65) * HD);
            vv2 = *(const ushort4*)(Vst + (size_t)(kt + 66) * HD);
            vv3 = *(const ushort4*)(Vst + (size_t)(kt + 67) * HD);
        }
        // ---- QK^T (swapped): s[jt] = S^T tile
        f32x4 s0[4], s1[4];
        #pragma unroll
        for (int jt = 0; jt < 4; ++jt) {
            bf16x8 kf0 = *(const bf16x8*)(&Kl[jt*16 + r][g*8]);
            bf16x8 kf1 = *(const bf16x8*)(&Kl[jt*16 + r][32 + g*8]);
            f32x4 z = {};
            s0[jt] = __builtin_amdgcn_mfma_f32_16x16x32_bf16(kf0, qf00, z, 0,0,0);
            s0[jt] = __builtin_amdgcn_mfma_f32_16x16x32_bf16(kf1, qf01, s0[jt], 0,0,0);
            s1[jt] = __builtin_amdgcn_mfma_f32_16x16x32_bf16(kf0, qf10, z, 0,0,0);
            s1[jt] = __builtin_amdgcn_mfma_f32_16x16x32_bf16(kf1, qf11, s1[jt], 0,0,0);
        }
        // ---- V frags (shared by both halves)
        bf16x8 vf[4][2];
        #pragma unroll
        for (int dt = 0; dt < 4; ++dt) {
            vf[dt][0] = *(const bf16x8*)(&Vt[dt*16 + r][g*8]);
            vf[dt][1] = *(const bf16x8*)(&Vt[dt*16 + r][32 + g*8]);
        }
        // ---- softmax + PV, half 0
        {
            float mx = s0[0][0];
            #pragma unroll
            for (int jt = 0; jt < 4; ++jt)
                #pragma unroll
                for (int rg = 0; rg < 4; ++rg) mx = fmaxf(mx, s0[jt][rg]);
            mx = fmaxf(mx, __shfl_xor(mx, 16));
            mx = fmaxf(mx, __shfl_xor(mx, 32));
            float mnew = fmaxf(m0r, mx);
            float a = exp2f(SCALE2 * (m0r - mnew));
            m0r = mnew;
            float cm = SCALE2 * mnew;
            float ps = 0.f;
            #pragma unroll
            for (int jt = 0; jt < 4; ++jt) {
                float p0 = exp2f(fmaf(SCALE2, s0[jt][0], -cm));
                float p1 = exp2f(fmaf(SCALE2, s0[jt][1], -cm));
                float p2 = exp2f(fmaf(SCALE2, s0[jt][2], -cm));
                float p3 = exp2f(fmaf(SCALE2, s0[jt][3], -cm));
                ps += (p0 + p1) + (p2 + p3);
                uint2 wrd; wrd.x = cvtpk(p0, p1); wrd.y = cvtpk(p2, p3);
                *(uint2*)(prow0 + ((32*jt + 8*g) ^ rx)) = wrd;
            }
            ps += __shfl_xor(ps, 16);
            ps += __shfl_xor(ps, 32);
            l0r = l0r * a + ps;
            #pragma unroll
            for (int dt = 0; dt < 4; ++dt) o0[dt] *= a;
            bf16x8 pb0 = *(const bf16x8*)(prow0 + ((16*g) ^ rx));
            bf16x8 pb1 = *(const bf16x8*)(prow0 + ((64 + 16*g) ^ rx));
            #pragma unroll
            for (int dt = 0; dt < 4; ++dt) {
                o0[dt] = __builtin_amdgcn_mfma_f32_16x16x32_bf16(vf[dt][0], pb0, o0[dt], 0,0,0);
                o0[dt] = __builtin_amdgcn_mfma_f32_16x16x32_bf16(vf[dt][1], pb1, o0[dt], 0,0,0);
            }
        }
        // ---- softmax + PV, half 1
        {
            float mx = s1[0][0];
            #pragma unroll
            for (int jt = 0; jt < 4; ++jt)
                #pragma unroll
                for (int rg = 0; rg < 4; ++rg) mx = fmaxf(mx, s1[jt][rg]);
            mx = fmaxf(mx, __shfl_xor(mx, 16));
            mx = fmaxf(mx, __shfl_xor(mx, 32));
            float mnew = fmaxf(m1r, mx);
            float a = exp2f(SCALE2 * (m1r - mnew));
            m1r = mnew;
            float cm = SCALE2 * mnew;
            float ps = 0.f;
            #pragma unroll
            for (int jt = 0; jt < 4; ++jt) {
                float p0 = exp2f(fmaf(SCALE2, s1[jt][0], -cm));
                float p1 = exp2f(fmaf(SCALE2, s1[jt][1], -cm));
                float p2 = exp2f(fmaf(SCALE2, s1[jt][2], -cm));
                float p3 = exp2f(fmaf(SCALE2, s1[jt][3], -cm));
                ps += (p0 + p1) + (p2 + p3);
                uint2 wrd; wrd.x = cvtpk(p0, p1); wrd.y = cvtpk(p2, p3);
                *(uint2*)(prow1 + ((32*jt + 8*g) ^ rx)) = wrd;
            }
            ps += __shfl_xor(ps, 16);
            ps += __shfl_xor(ps, 32);
            l1r = l1r * a + ps;
            #pragma unroll
            for (int dt = 0; dt < 4; ++dt) o1[dt] *= a;
            bf16x8 pb0 = *(const bf16x8*)(prow1 + ((16*g) ^ rx));
            bf16x8 pb1 = *(const bf16x8*)(prow1 + ((64 + 16*g) ^ rx));
            #pragma unroll
            for (int dt = 0; dt < 4; ++dt) {
                o1[dt] = __builtin_amdgcn_mfma_f32_16x16x32_bf16(vf[dt][0], pb0, o1[dt], 0,0,0);
                o1[dt] = __builtin_amdgcn_mfma_f32_16x16x32_bf16(vf[dt][1], pb1, o1[dt], 0,0,0);
            }
        }
        __syncthreads();
        if (more) {
            *(bf16x8*)(&Kl[skv][sd]) = kk0;
            *(bf16x8*)(&Kl[skv][sd + 8]) = kk1;
            #pragma unroll
            for (int i = 0; i < 4; ++i) {
                unsigned lo = (unsigned)((const unsigned short*)&vv0)[i]
                            | ((unsigned)((const unsigned short*)&vv1)[i] << 16);
                unsigned hi = (unsigned)((const unsigned short*)&vv2)[i]
                            | ((unsigned)((const unsigned short*)&vv3)[i] << 16);
                uint2 wrd; wrd.x = lo; wrd.y = hi;
                *(uint2*)(&Vt[vd + i][vkv]) = wrd;
            }
        }
    }
    // epilogue: O^T lane (g,r) holds O[q][d=dt*16+g*4+rg]; float4 stores
    float inv0 = 1.0f / l0r, inv1 = 1.0f / l1r;
    #pragma unroll
    for (int dt = 0; dt < 4; ++dt) {
        float4 v0, v1;
        v0.x = o0[dt][0]*inv0; v0.y = o0[dt][1]*inv0;
        v0.z = o0[dt][2]*inv0; v0.w = o0[dt][3]*inv0;
        v1.x = o1[dt][0]*inv1; v1.y = o1[dt][1]*inv1;
        v1.z = o1[dt][2]*inv1; v1.w = o1[dt][3]*inv1;
        *(float4*)(out + (size_t)(b*NSEQ + q0 + r)*EDIM + h*HD + dt*16 + g*4) = v0;
        *(float4*)(out + (size_t)(b*NSEQ + q0 + 16 + r)*EDIM + h*HD + dt*16 + g*4) = v1;
    }
}

extern "C" void kernel_launch(void* const* d_in, const int* in_sizes, int n_in,
                              void* d_out, int out_size, void* d_ws, size_t ws_size,
                              hipStream_t stream) {
    const float* x  = (const float*)d_in[0];
    const float* w  = (const float*)d_in[1];
    const float* bq = (const float*)d_in[2];
    float* outp = (float*)d_out;
    char* ws = (char*)d_ws;
    short* Xb  = (short*)(ws);
    short* Wt  = (short*)(ws + 8388608);
    float* Bp  = (float*)(ws + 8388608 + 6291456);
    short* QKV = (short*)(ws + 8388608 + 6291456 + 16384);
    k_convert_x<<<dim3(2048), dim3(256), 0, stream>>>(x, Xb, (MTOT*EDIM)/4);
    k_transpose_w<<<dim3(16, 32), dim3(256), 0, stream>>>(w, Wt);
    k_perm_bias<<<dim3(12), dim3(256), 0, stream>>>(bq, Bp);
    k_qkv_gemm<<<dim3(32, 24), dim3(256), 0, stream>>>(Xb, Wt, Bp, QKV);
    k_attn<<<dim3(16, 16, 2), dim3(256), 0, stream>>>(QKV, outp);
}